// Round 2
// baseline (457.174 us; speedup 1.0000x reference)
//
#include <hip/hip_runtime.h>
#include <math.h>

#define N_NODES 100000
#define N_EDGES 1600000
#define D_IN 256
#define D_OUT 128

// ---- workspace layout (bytes) ------------------------------------------
#define OFF_SUPPORT 0
#define OFF_COUNTS  51200000
#define OFF_CSREV   51600008
#define OFF_BSUMS   64400008
#define OFF_WTHI    64400416
#define OFF_WTLO    64465952

#define SCAN_CHUNK  1024
#define SCAN_BLOCKS ((N_NODES + SCAN_CHUNK - 1) / SCAN_CHUNK)  // 98

#define GB 128                                    // node rows per GEMM tile
#define GEMM_BLOCKS (((N_NODES + GB - 1) / GB) * 2)  // 1564: x2 col-halves
#define EDGE_BLOCKS ((N_EDGES + 255) / 256)       // 6250

typedef __attribute__((ext_vector_type(8))) short s8v;   // 8 bf16 = 4 VGPR
typedef __attribute__((ext_vector_type(4))) float f4v;   // mfma acc

__device__ __forceinline__ short f2bf(float x) {   // RNE fp32 -> bf16 bits
  unsigned u = __float_as_uint(x);
  unsigned r = u + 0x7FFF + ((u >> 16) & 1);
  return (short)(r >> 16);
}
__device__ __forceinline__ float bf2f(short h) {
  return __uint_as_float(((unsigned)(unsigned short)h) << 16);
}

// split 8 fp32 into bf16 hi/lo fragments (in-register)
__device__ __forceinline__ void cvt8(float4 a, float4 b, s8v& h, s8v& l) {
  float f[8] = {a.x, a.y, a.z, a.w, b.x, b.y, b.z, b.w};
#pragma unroll
  for (int i = 0; i < 8; i++) {
    short hh = f2bf(f[i]);
    h[i] = hh;
    l[i] = f2bf(f[i] - bf2f(hh));
  }
}

typedef const float __attribute__((address_space(1)))* gas1f;
typedef float __attribute__((address_space(3)))* las3f;
__device__ __forceinline__ void gload_lds16(const float* g, float* l) {
  // wave-uniform LDS base; HW writes base + lane*16; global addr per-lane
  __builtin_amdgcn_global_load_lds((gas1f)g, (las3f)l, 16, 0, 0);
}

// ---------------------------------------------------------------------------
// K0: W[k][n] fp32 -> wt_hi/wt_lo[n][k] bf16 split (once; 32K elems)
// ---------------------------------------------------------------------------
__global__ __launch_bounds__(256) void wconv_kernel(
    const float* __restrict__ W, short* __restrict__ wt_hi,
    short* __restrict__ wt_lo) {
  int idx = blockIdx.x * 256 + threadIdx.x;
  int k = idx >> 7;
  int n = idx & 127;
  float v = W[idx];
  short h = f2bf(v);
  wt_hi[n * 256 + k] = h;
  wt_lo[n * 256 + k] = f2bf(v - bf2f(h));
}

// ---------------------------------------------------------------------------
// Barrier-free split-bf16 MFMA GEMM: support = X*W + b.
//  - per-wave-private A slices (wave wv only ever reads rows wv*32..+31)
//    -> NO __syncthreads anywhere; sync is vmcnt only.
//  - A staged via global_load_lds DMA, double-buffered, XOR-swizzled
//    source (chunk s^(row&7)) so swizzled b128 reads are conflict-free.
//  - B (wt tables, 128KB, L1/L2-resident) loaded direct to registers
//    BEFORE the stage issue -> compiler's pre-MFMA wait is vmcnt(4),
//    leaving the next tile's DMA in flight across the MFMA phase.
//  - N split across blocks (64 cols each) to stay under 128 VGPR.
// Same fragment math as the verified round-0 kernel -> same absmax.
// ---------------------------------------------------------------------------
__device__ __forceinline__ void gemm_body(
    int gb, const float* __restrict__ input, const short* __restrict__ wt_hi,
    const short* __restrict__ wt_lo, const float* __restrict__ b,
    float* __restrict__ support) {
  __shared__ float Af[4][2][32][32];   // 32 KB: wave x dbuf x row x k
  const int t = threadIdx.x;
  const int lane = t & 63;
  const int wv = t >> 6;
  const int qm = lane & 15;
  const int quad = lane >> 4;
  const int tile_m = gb >> 1;
  const int ch = gb & 1;               // column half (0: cols 0-63, 1: 64-127)
  const int node0 = tile_m * GB;
  const int col0 = ch * 64;

  const int srow = lane >> 3;          // 0..7
  const int gc = (lane & 7) ^ srow;    // swizzled 16B-chunk in source row

  auto stage = [&](int kt, int buf) {
#pragma unroll
    for (int j = 0; j < 4; ++j) {
      int nd = node0 + wv * 32 + j * 8 + srow;
      if (nd > N_NODES - 1) nd = N_NODES - 1;   // clamp; garbage never stored
      gload_lds16(input + (size_t)nd * D_IN + kt * 32 + gc * 4,
                  &Af[wv][buf][j * 8][0]);
    }
  };

  stage(0, 0);

  f4v acc[2][4];
#pragma unroll
  for (int mt = 0; mt < 2; mt++)
#pragma unroll
    for (int nt = 0; nt < 4; nt++) acc[mt][nt] = (f4v){0.f, 0.f, 0.f, 0.f};

  const int p0 = (2 * quad) ^ (qm & 7);      // physical chunk of logical 2q
  const int p1 = (2 * quad + 1) ^ (qm & 7);  // physical chunk of logical 2q+1

#pragma unroll
  for (int kt = 0; kt < 8; ++kt) {
    const int cb = kt & 1;
    // guarantee stage(kt) DMA complete before reading its buffer
    asm volatile("s_waitcnt vmcnt(0)" ::: "memory");
    float4 x00 = *(const float4*)&Af[wv][cb][qm][p0 * 4];
    float4 x01 = *(const float4*)&Af[wv][cb][qm][p1 * 4];
    float4 x10 = *(const float4*)&Af[wv][cb][qm + 16][p0 * 4];
    float4 x11 = *(const float4*)&Af[wv][cb][qm + 16][p1 * 4];

    const int koff = kt * 32 + quad * 8;
    s8v bh[4], bl[4];
#pragma unroll
    for (int nt = 0; nt < 4; ++nt) {
      size_t bo = (size_t)(col0 + nt * 16 + qm) * 256 + koff;
      bh[nt] = *(const s8v*)(wt_hi + bo);
      bl[nt] = *(const s8v*)(wt_lo + bo);
    }
    __builtin_amdgcn_sched_barrier(0);
    if (kt < 7) stage(kt + 1, cb ^ 1);   // DMA next tile; stays in flight
    __builtin_amdgcn_sched_barrier(0);

    s8v ah0, al0, ah1, al1;
    cvt8(x00, x01, ah0, al0);
    cvt8(x10, x11, ah1, al1);
#pragma unroll
    for (int nt = 0; nt < 4; ++nt) {
      acc[0][nt] = __builtin_amdgcn_mfma_f32_16x16x32_bf16(ah0, bh[nt], acc[0][nt], 0, 0, 0);
      acc[0][nt] = __builtin_amdgcn_mfma_f32_16x16x32_bf16(ah0, bl[nt], acc[0][nt], 0, 0, 0);
      acc[0][nt] = __builtin_amdgcn_mfma_f32_16x16x32_bf16(al0, bh[nt], acc[0][nt], 0, 0, 0);
      acc[1][nt] = __builtin_amdgcn_mfma_f32_16x16x32_bf16(ah1, bh[nt], acc[1][nt], 0, 0, 0);
      acc[1][nt] = __builtin_amdgcn_mfma_f32_16x16x32_bf16(ah1, bl[nt], acc[1][nt], 0, 0, 0);
      acc[1][nt] = __builtin_amdgcn_mfma_f32_16x16x32_bf16(al1, bh[nt], acc[1][nt], 0, 0, 0);
    }
  }

  float bias[4];
#pragma unroll
  for (int nt = 0; nt < 4; nt++) bias[nt] = b[col0 + nt * 16 + qm];
#pragma unroll
  for (int mt = 0; mt < 2; mt++) {
#pragma unroll
    for (int nt = 0; nt < 4; nt++) {
      int col = col0 + nt * 16 + qm;
#pragma unroll
      for (int r = 0; r < 4; r++) {
        int node = node0 + wv * 32 + mt * 16 + quad * 4 + r;
        if (node < N_NODES)
          support[(size_t)node * D_OUT + col] = acc[mt][nt][r] + bias[nt];
      }
    }
  }
}

// K1: FULL GEMM || FULL hist (GEMM blocks first to seed the CUs)
__global__ __launch_bounds__(256, 4) void gemm_hist_kernel(
    const float* __restrict__ input, const short* __restrict__ wt_hi,
    const short* __restrict__ wt_lo, const float* __restrict__ b,
    float* __restrict__ support, const int* __restrict__ erow,
    int* __restrict__ counts, int* __restrict__ pos_e) {
  if (blockIdx.x < GEMM_BLOCKS) {
    gemm_body(blockIdx.x, input, wt_hi, wt_lo, b, support);
  } else {
    int e = (blockIdx.x - GEMM_BLOCKS) * 256 + threadIdx.x;
    if (e < N_EDGES) pos_e[e] = atomicAdd(&counts[erow[e]], 1);
  }
}

// K2: atomic-free CSR bucket scatter
__global__ __launch_bounds__(256) void build_kernel(
    const int* __restrict__ erow, const int* __restrict__ ecol,
    const float* __restrict__ eval, const int* __restrict__ offsets,
    const int* __restrict__ pos_e, int2* __restrict__ csr_ev) {
  int e = blockIdx.x * 256 + threadIdx.x;
  if (e < N_EDGES) {
    int idx = offsets[erow[e]] + pos_e[e];
    csr_ev[idx] = make_int2(ecol[e], __float_as_int(eval[e]));
  }
}

// ---------------------------------------------------------------------------
// 3-phase exclusive scan over counts (verified)
// ---------------------------------------------------------------------------
__global__ __launch_bounds__(256) void scan_phase1(const int* __restrict__ counts,
                                                   int* __restrict__ bsums) {
  __shared__ int ts[256];
  int t = threadIdx.x;
  int idx0 = blockIdx.x * SCAN_CHUNK + t * 4;
  int s = 0;
#pragma unroll
  for (int i = 0; i < 4; i++)
    if (idx0 + i < N_NODES) s += counts[idx0 + i];
  ts[t] = s;
  __syncthreads();
#pragma unroll
  for (int off = 128; off > 0; off >>= 1) {
    if (t < off) ts[t] += ts[t + off];
    __syncthreads();
  }
  if (t == 0) bsums[blockIdx.x] = ts[0];
}

__global__ __launch_bounds__(128) void scan_phase2(int* __restrict__ bsums) {
  __shared__ int s[128];
  int t = threadIdx.x;
  int v = (t < SCAN_BLOCKS) ? bsums[t] : 0;
  s[t] = v;
  __syncthreads();
#pragma unroll
  for (int off = 1; off < 128; off <<= 1) {
    int x = (t >= off) ? s[t - off] : 0;
    __syncthreads();
    s[t] += x;
    __syncthreads();
  }
  if (t < SCAN_BLOCKS) bsums[t] = s[t] - v;  // exclusive
}

__global__ __launch_bounds__(256) void scan_phase3(int* __restrict__ counts,
                                                   const int* __restrict__ bsums) {
  __shared__ int ts[256];
  int t = threadIdx.x;
  int b = blockIdx.x;
  int idx0 = b * SCAN_CHUNK + t * 4;
  int v[4];
  int s = 0;
#pragma unroll
  for (int i = 0; i < 4; i++) {
    v[i] = (idx0 + i < N_NODES) ? counts[idx0 + i] : 0;
    s += v[i];
  }
  ts[t] = s;
  __syncthreads();
#pragma unroll
  for (int off = 1; off < 256; off <<= 1) {
    int x = (t >= off) ? ts[t - off] : 0;
    __syncthreads();
    ts[t] += x;
    __syncthreads();
  }
  int run = bsums[b] + ts[t] - s;
#pragma unroll
  for (int i = 0; i < 4; i++) {
    int idx = idx0 + i;
    if (idx < N_NODES) counts[idx] = run;
    run += v[i];
  }
  if (b == 0 && t == 0) counts[N_NODES] = N_EDGES;
}

// ---------------------------------------------------------------------------
// Gather-aggregate + fused tanh.  32 lanes x float4 per row.
// ---------------------------------------------------------------------------
__global__ __launch_bounds__(256) void agg_kernel(
    const int* __restrict__ offsets, const int2* __restrict__ csr_ev,
    const float* __restrict__ support, float* __restrict__ out) {
  int r = blockIdx.x * 8 + (threadIdx.x >> 5);
  int l4 = (threadIdx.x & 31) * 4;          // feature quad
  int beg = offsets[r];
  int end = offsets[r + 1];
  float4 acc = make_float4(0.f, 0.f, 0.f, 0.f);
  int j = beg;
  for (; j + 8 <= end; j += 8) {
    int2 e[8];
    float4 s[8];
#pragma unroll
    for (int u = 0; u < 8; u++) e[u] = csr_ev[j + u];
#pragma unroll
    for (int u = 0; u < 8; u++)
      s[u] = *(const float4*)(support + (size_t)e[u].x * D_OUT + l4);
#pragma unroll
    for (int u = 0; u < 8; u++) {
      float v = __int_as_float(e[u].y);
      acc.x = fmaf(v, s[u].x, acc.x);
      acc.y = fmaf(v, s[u].y, acc.y);
      acc.z = fmaf(v, s[u].z, acc.z);
      acc.w = fmaf(v, s[u].w, acc.w);
    }
  }
  for (; j < end; j++) {
    int2 ev = csr_ev[j];
    float4 s = *(const float4*)(support + (size_t)ev.x * D_OUT + l4);
    float v = __int_as_float(ev.y);
    acc.x = fmaf(v, s.x, acc.x);
    acc.y = fmaf(v, s.y, acc.y);
    acc.z = fmaf(v, s.z, acc.z);
    acc.w = fmaf(v, s.w, acc.w);
  }
  *(float4*)(out + (size_t)r * D_OUT + l4) =
      make_float4(tanhf(acc.x), tanhf(acc.y), tanhf(acc.z), tanhf(acc.w));
}

extern "C" void kernel_launch(void* const* d_in, const int* in_sizes, int n_in,
                              void* d_out, int out_size, void* d_ws, size_t ws_size,
                              hipStream_t stream) {
  const float* input = (const float*)d_in[0];
  const int* erow = (const int*)d_in[1];
  const int* ecol = (const int*)d_in[2];
  const float* eval = (const float*)d_in[3];
  const float* W = (const float*)d_in[4];
  const float* b = (const float*)d_in[5];
  float* out = (float*)d_out;

  char* ws = (char*)d_ws;
  float* support = (float*)(ws + OFF_SUPPORT);
  int* counts = (int*)(ws + OFF_COUNTS);  // becomes offsets after scan
  int2* csr_ev = (int2*)(ws + OFF_CSREV);
  int* bsums = (int*)(ws + OFF_BSUMS);
  short* wt_hi = (short*)(ws + OFF_WTHI);
  short* wt_lo = (short*)(ws + OFF_WTLO);
  int* pos_e = (int*)d_out;  // d_out as scratch; agg overwrites it last

  // K0: convert W once (transposed bf16 hi/lo)
  hipLaunchKernelGGL(wconv_kernel, dim3((D_IN * D_OUT) / 256), dim3(256), 0,
                     stream, W, wt_hi, wt_lo);
  hipMemsetAsync(ws + OFF_COUNTS, 0, (size_t)(N_NODES + 1) * 4, stream);

  // K1: full MFMA-GEMM || full histogram
  hipLaunchKernelGGL(gemm_hist_kernel, dim3(GEMM_BLOCKS + EDGE_BLOCKS),
                     dim3(256), 0, stream, input, wt_hi, wt_lo, b, support,
                     erow, counts, pos_e);
  // exclusive scan: counts -> offsets
  hipLaunchKernelGGL(scan_phase1, dim3(SCAN_BLOCKS), dim3(256), 0, stream,
                     counts, bsums);
  hipLaunchKernelGGL(scan_phase2, dim3(1), dim3(128), 0, stream, bsums);
  hipLaunchKernelGGL(scan_phase3, dim3(SCAN_BLOCKS), dim3(256), 0, stream,
                     counts, bsums);
  // K2: atomic-free CSR bucket scatter
  hipLaunchKernelGGL(build_kernel, dim3(EDGE_BLOCKS), dim3(256), 0, stream,
                     erow, ecol, eval, counts, pos_e, csr_ev);
  // out = tanh(A_csr * support)
  hipLaunchKernelGGL(agg_kernel, dim3(N_NODES / 8), dim3(256), 0, stream,
                     counts, csr_ev, support, out);
}